// Round 15
// baseline (59.821 us; speedup 1.0000x reference)
//
#include <hip/hip_runtime.h>
#include <hip/hip_bf16.h>

// B=8, Lq=2048, Lk=2048, D=256. out = softmax(mask? sq_i+sk_j : -1e9) @ V.
// sq cancels in softmax => out[i] = (mask[i]·(e*V)) / (mask[i]·e), e=exp(K·w).
// Kernel 1: eb (bf16) + evB (pre-fragmented MFMA B-operand).
// Kernel 2: mask-streaming GEMM, BM=64 x BN=256 x BK=64, 512 thr (8 waves,
//   2m x 4n), grid 256 = 1 block/CU, mask read exactly once. B DEDUPED through
//   LDS: each step's 32 x 1KB fragments staged ONCE via global_load_lds, read
//   back by conflict-free linear ds_read_b128 (L1 bytes/CU-step 80->48 KB).
//   ROUND-15 FIX: bare end-of-step s_barrier — the mid-step barrier alone left
//   a race (fast wave's gld_lds into B_s[nxt] vs slow wave's step t-1 reads of
//   the same buffer; rounds 3-5 were safe only because their barrier sat after
//   compute). Mid-step wait stays s_waitcnt vmcnt(2) lgkmcnt(0) (A(t+2) flat
//   loads in flight — vmcnt never drained to 0). A: 3-ring, 2-step reg
//   prefetch, XOR slot (0-conflict). Denominator folded into MFMA (e-column
//   B-frag, wn==0 waves).
// Workspace: evB 8 MB + eb 32 KB.

#define NB 8
#define LQ 2048
#define LK 2048
#define DD 256

typedef __attribute__((ext_vector_type(8))) short short8v;
typedef __attribute__((ext_vector_type(8))) unsigned short ushort8v;
typedef __attribute__((ext_vector_type(4))) float f32x4;

__device__ inline unsigned short f2bf(float x) {
  union { __hip_bfloat16 h; unsigned short u; } cv;
  cv.h = __float2bfloat16(x);
  return cv.u;
}

__device__ inline uint4 pack_mask8(const int4 a, const int4 b) {
  uint4 p;
  p.x = (a.x ? 0x3F80u : 0u) | (a.y ? 0x3F800000u : 0u);
  p.y = (a.z ? 0x3F80u : 0u) | (a.w ? 0x3F800000u : 0u);
  p.z = (b.x ? 0x3F80u : 0u) | (b.y ? 0x3F800000u : 0u);
  p.w = (b.z ? 0x3F80u : 0u) | (b.w ? 0x3F800000u : 0u);
  return p;
}

__device__ inline void gld_lds16(const unsigned short* g, unsigned short* l) {
  __builtin_amdgcn_global_load_lds(
      (const __attribute__((address_space(1))) void*)g,
      (__attribute__((address_space(3))) void*)l, 16, 0, 0);
}

// ---------------- Kernel 1: eb = bf16(exp(K·w)); evB = pre-fragmented e*V -----
// grid 8*64=512 (b = blk&7 -> XCD), 256 thr. Block owns batch b, 32 j-rows (ks).
__global__ __launch_bounds__(256) void bah_precompute(
    const float* __restrict__ key, const float* __restrict__ value,
    const float* __restrict__ w, unsigned short* __restrict__ evB,
    unsigned short* __restrict__ eb)
{
  __shared__ float e_s[32];
  __shared__ unsigned short t_s[32][260];   // padded: conflict-free transpose

  const int t = threadIdx.x;
  const int lane = t & 63;
  const int wid = t >> 6;                   // 0..3
  const int blk = blockIdx.x;
  const int b = blk & 7;
  const int ks = blk >> 3;                  // 0..63 (32-k slice)
  const int j0 = ks * 32;

  const float4 wv4 = reinterpret_cast<const float4*>(w)[lane];

#pragma unroll
  for (int r8 = 0; r8 < 8; ++r8) {
    const int r = wid * 8 + r8;
    const size_t row = (size_t)b * LK + j0 + r;
    const float4 kv = reinterpret_cast<const float4*>(key + row * DD)[lane];
    float s = kv.x * wv4.x + kv.y * wv4.y + kv.z * wv4.z + kv.w * wv4.w;
#pragma unroll
    for (int off = 32; off; off >>= 1) s += __shfl_xor(s, off);
    const float e = __expf(s);              // |K·w| small: no max-shift needed
    if (lane == 0) { e_s[r] = e; eb[row] = f2bf(e); }
  }
  __syncthreads();

#pragma unroll
  for (int g = 0; g < 8; ++g) {
    const int jr = g * 4 + wid;
    const size_t row = (size_t)b * LK + j0 + jr;
    const float4 vv = reinterpret_cast<const float4*>(value + row * DD)[lane];
    const float e = e_s[jr];
    ushort4 u;
    u.x = f2bf(e * vv.x);
    u.y = f2bf(e * vv.y);
    u.z = f2bf(e * vv.z);
    u.w = f2bf(e * vv.w);
    *reinterpret_cast<ushort4*>(&t_s[jr][lane * 4]) = u;
  }
  __syncthreads();

  // frag gather: lane holds B[k=8*(lane>>4)+i][d=n*16+(lane&15)]
  const int lr = lane & 15;
  const int lj = lane >> 4;
#pragma unroll
  for (int n4 = 0; n4 < 4; ++n4) {
    const int n = wid * 4 + n4;
    ushort8v va;
#pragma unroll
    for (int i = 0; i < 8; ++i) va[i] = t_s[lj * 8 + i][n * 16 + lr];
    *reinterpret_cast<ushort8v*>(
        evB + ((size_t)((b * 64 + ks) * 16 + n) * 64 + lane) * 8) = va;
  }
}

// ---------------- Kernel 2: mask-streaming masked GEMM, LDS-deduped B ---------
// grid 256 (1 block/CU): blk = b + 8*itile. 512 thr = 8 waves (2m x 4n).
// Block tile: 64 rows x 256 d; wave (wm,wn): rows [wm*32,+32), d [wn*64,+64).
__global__ __launch_bounds__(512, 1) void bah_gemm(
    const int* __restrict__ mask, const unsigned short* __restrict__ evB,
    const unsigned short* __restrict__ eb, float* __restrict__ out)
{
  __shared__ unsigned short A_s[3][64 * 64];    // 24.6 KB A ring, XOR-swizzled
  __shared__ unsigned short B_s[2][32 * 512];   // 64 KB: 32 frags x 1KB, linear
  __shared__ float denom_s[64];

  const int t = threadIdx.x;
  const int lane = t & 63;
  const int wid = t >> 6;                   // 0..7
  const int wm = wid >> 2;                  // 0..1: 32-row half
  const int wn = wid & 3;                   // 0..3: 64-d quarter
  const int lr = lane & 15;
  const int lj = lane >> 4;

  const int blk = blockIdx.x;
  const int b = blk & 7;                    // batch -> XCD (evB L2-resident)
  const int i0 = (blk >> 3) * 64;

  // ---- A staging: 8 thr/row; thread owns ints [q*8,q*8+8) = 32 B contiguous
  //      -> one uint4 (8 bf16) -> LDS slot q ^ (sr&7). (round-13, 0-conflict) --
  const int sr = t >> 3;                    // 0..63
  const int q = t & 7;
  const int* aptr = mask + ((size_t)b * LQ + i0 + sr) * LK + q * 8;
  const int awr = sr * 64 + ((q ^ (sr & 7)) * 8);

  // ---- B staging via gld_lds: wave (wm,wn) fills frags (h=wm, n=wn*4+nn) ----
  const unsigned short* evBb = evB + (size_t)b * 64 * 16 * 512;
  const int bfrag = (wm * 16 + wn * 4) * 512;   // LDS ushort base of wave's frags
  const unsigned short* ebb = eb + b * LK + lj * 8;

  // A frag read offsets: row = wm*32 + m*16 + lr; chunk (h*4+lj) ^ (row&7)
  int afo[2][2];
#pragma unroll
  for (int m = 0; m < 2; ++m) {
    const int row = wm * 32 + m * 16 + lr;
#pragma unroll
    for (int h = 0; h < 2; ++h)
      afo[m][h] = row * 64 + (((h * 4 + lj) ^ (row & 7)) * 8);
  }
  // B frag read offsets: (h*16 + wn*4+nn)*512 + lane*8
  const int bro = wn * 4 * 512 + lane * 8;

  f32x4 acc[2][4] = {};
  f32x4 accd[2] = {};
  const short8v z8 = {};
  short8v efr[2][2] = {{z8, z8}, {z8, z8}};

  // ---- prologue: A(0)->ring0; A(1)->regs; B(0)->B_s[0]; e(0)->regs ----
  {
    const int4 p0 = *reinterpret_cast<const int4*>(aptr);
    const int4 p1 = *reinterpret_cast<const int4*>(aptr + 4);
    *reinterpret_cast<uint4*>(&A_s[0][awr]) = pack_mask8(p0, p1);
  }
  int4 aC0 = *reinterpret_cast<const int4*>(aptr + 64);
  int4 aC1 = *reinterpret_cast<const int4*>(aptr + 68);
#pragma unroll
  for (int nn = 0; nn < 4; ++nn)            // frag ks = 0+wm, n = wn*4+nn
    gld_lds16(evBb + ((size_t)(0 + wm) * 16 + wn * 4 + nn) * 512 + lane * 8,
              &B_s[0][bfrag + nn * 512]);
  if (wn == 0 && lr == 0) {
    efr[0][0] = *reinterpret_cast<const short8v*>(ebb + 0);
    efr[0][1] = *reinterpret_cast<const short8v*>(ebb + 32);
  }
  __syncthreads();

#pragma unroll 2
  for (int tt = 0; tt < 32; ++tt) {
    const int cur = tt & 1;
    const int nxt = cur ^ 1;
    const int bufC = tt % 3;
    const int bufW = (tt + 1) % 3;

    // ---- 1) gld_lds B(t+1) FIRST (oldest in vmcnt order). Safe vs step t-1
    //         readers of B_s[nxt] because of the END-OF-STEP barrier below. ----
    const int p1 = (tt + 1) & 31;           // wrap: dead fill, harmless
#pragma unroll
    for (int nn = 0; nn < 4; ++nn)
      gld_lds16(evBb + ((size_t)(2 * p1 + wm) * 16 + wn * 4 + nn) * 512 + lane * 8,
                &B_s[nxt][bfrag + nn * 512]);
    __builtin_amdgcn_sched_barrier(0);

    // ---- 2) e(t+1) regs ----
    if (wn == 0 && lr == 0) {
      efr[nxt][0] = *reinterpret_cast<const short8v*>(ebb + p1 * 64);
      efr[nxt][1] = *reinterpret_cast<const short8v*>(ebb + p1 * 64 + 32);
    }
    __builtin_amdgcn_sched_barrier(0);

    // ---- 3) A(t+2) flat loads (newest: allowed to stay in flight) ----
    const int k2 = ((tt + 2) & 31) * 64;
    const int4 aN0 = *reinterpret_cast<const int4*>(aptr + k2);
    const int4 aN1 = *reinterpret_cast<const int4*>(aptr + k2 + 4);
    __builtin_amdgcn_sched_barrier(0);

    // ---- 4) write A(t+1) from regs; certify B_s[nxt]+A_s[bufW] ----
    *reinterpret_cast<uint4*>(&A_s[bufW][awr]) = pack_mask8(aC0, aC1);
    asm volatile("s_waitcnt vmcnt(2) lgkmcnt(0)" ::: "memory");
    __builtin_amdgcn_sched_barrier(0);
    __builtin_amdgcn_s_barrier();
    __builtin_amdgcn_sched_barrier(0);

    // ---- 5) compute tile t from LDS-A + LDS-B ----
#pragma unroll
    for (int h = 0; h < 2; ++h) {
      short8v af[2], bf[4];
#pragma unroll
      for (int m = 0; m < 2; ++m)
        af[m] = *reinterpret_cast<const short8v*>(&A_s[bufC][afo[m][h]]);
#pragma unroll
      for (int nn = 0; nn < 4; ++nn)
        bf[nn] = *reinterpret_cast<const short8v*>(
            &B_s[cur][h * 16 * 512 + bro + nn * 512]);
      __builtin_amdgcn_s_setprio(1);
      if (wn == 0) {
#pragma unroll
        for (int m = 0; m < 2; ++m)
          accd[m] = __builtin_amdgcn_mfma_f32_16x16x32_bf16(
              af[m], efr[cur][h], accd[m], 0, 0, 0);
      }
#pragma unroll
      for (int m = 0; m < 2; ++m)
#pragma unroll
        for (int nn = 0; nn < 4; ++nn)
          acc[m][nn] = __builtin_amdgcn_mfma_f32_16x16x32_bf16(
              af[m], bf[nn], acc[m][nn], 0, 0, 0);
      __builtin_amdgcn_s_setprio(0);
    }

    // ---- 6) END-OF-STEP rendezvous: all B_s[cur] reads done before any wave
    //         issues next step's gld_lds into B_s[cur]. Bare barrier: no
    //         waitcnt, global loads stay in flight. ----
    __builtin_amdgcn_sched_barrier(0);
    __builtin_amdgcn_s_barrier();
    __builtin_amdgcn_sched_barrier(0);

    aC0 = aN0; aC1 = aN1;
  }

  // ---- denominator broadcast (C col 0 lives in lanes with lr==0) ----
  if (wn == 0 && lr == 0) {
#pragma unroll
    for (int m = 0; m < 2; ++m)
#pragma unroll
      for (int qq = 0; qq < 4; ++qq)
        denom_s[wm * 32 + m * 16 + lj * 4 + qq] = accd[m][qq];
  }
  __syncthreads();

  // ---- epilogue: divide and store (C layout: col=lane&15, row=lj*4+q) ----
#pragma unroll
  for (int m = 0; m < 2; ++m) {
    const int row0 = wm * 32 + m * 16 + lj * 4;
    float inv[4];
#pragma unroll
    for (int qq = 0; qq < 4; ++qq) {
      const float dn = denom_s[row0 + qq];
      inv[qq] = (dn != 0.f) ? 1.f / dn : 0.f;   // all-masked row: avoid NaN
    }
#pragma unroll
    for (int nn = 0; nn < 4; ++nn) {
      const int col = wn * 64 + nn * 16 + lr;
#pragma unroll
      for (int qq = 0; qq < 4; ++qq)
        out[((size_t)b * LQ + (i0 + row0 + qq)) * DD + col] = acc[m][nn][qq] * inv[qq];
    }
  }
}

extern "C" void kernel_launch(void* const* d_in, const int* in_sizes, int n_in,
                              void* d_out, int out_size, void* d_ws, size_t ws_size,
                              hipStream_t stream) {
  // inputs: 0=query (unused: softmax shift-invariance), 1=key, 2=value, 3=mask, 4=w_align
  const float* key   = (const float*)d_in[1];
  const float* value = (const float*)d_in[2];
  const int*   mask  = (const int*)d_in[3];
  const float* w     = (const float*)d_in[4];
  float* out = (float*)d_out;

  unsigned short* evB = (unsigned short*)d_ws;                              // 8 MB
  unsigned short* eb  = (unsigned short*)((char*)d_ws + (size_t)NB * DD * LK * 2);

  bah_precompute<<<NB * (LK / 32), 256, 0, stream>>>(key, value, w, evB, eb);
  bah_gemm<<<256, 512, 0, stream>>>(mask, evB, eb, out);
}

// Round 16
// 50.712 us; speedup vs baseline: 1.1796x; 1.1796x over previous
//
#include <hip/hip_runtime.h>
#include <hip/hip_bf16.h>

// B=8, Lq=2048, Lk=2048, D=256. out = softmax(mask? sq_i+sk_j : -1e9) @ V.
// sq cancels in softmax => out[i] = (mask[i]·(e*V)) / (mask[i]·e), e=exp(K·w).
// FINAL (= round-10 empirical best, 50.6 us):
// Kernel 1: eb (bf16) + evB (pre-fragmented MFMA B-operand; coalesced loads).
// Kernel 2: mask-streaming GEMM, BM=128 x BN=128 x BK=64, 512 thr (8 waves,
//   2m x 4n). A-staging loads CONTIGUOUS per 4 lanes (16 rows x 64 B full
//   sectors per wave instr). LDS per-row rotation swizzle slot=(chunk+row)&7:
//   ~0 conflicts on b64 writes and b128 frag reads. A: 3-deep LDS ring, 2-step
//   reg prefetch. B/e: reg prefetch 1 step ahead from L2-resident evB.
//   Sync: lgkmcnt(0)+s_barrier only — vmcnt never drained. Denominator folded
//   into MFMA (e-column B-frag, wn==0 waves).
// Workspace: evB 8 MB + eb 32 KB.

#define NB 8
#define LQ 2048
#define LK 2048
#define DD 256

typedef __attribute__((ext_vector_type(8))) short short8v;
typedef __attribute__((ext_vector_type(8))) unsigned short ushort8v;
typedef __attribute__((ext_vector_type(4))) float f32x4;

__device__ inline unsigned short f2bf(float x) {
  union { __hip_bfloat16 h; unsigned short u; } cv;
  cv.h = __float2bfloat16(x);
  return cv.u;
}

__device__ inline uint2 pack_mask4(const int4 a) {
  uint2 p;
  p.x = (a.x ? 0x3F80u : 0u) | (a.y ? 0x3F800000u : 0u);
  p.y = (a.z ? 0x3F80u : 0u) | (a.w ? 0x3F800000u : 0u);
  return p;
}

// ---------------- Kernel 1: eb = bf16(exp(K·w)); evB = pre-fragmented e*V -----
// grid 8*64=512 (b = blk&7 -> XCD), 256 thr. Block owns batch b, 32 j-rows (ks).
__global__ __launch_bounds__(256) void bah_precompute(
    const float* __restrict__ key, const float* __restrict__ value,
    const float* __restrict__ w, unsigned short* __restrict__ evB,
    unsigned short* __restrict__ eb)
{
  __shared__ float e_s[32];
  __shared__ unsigned short t_s[32][260];   // padded: conflict-free transpose

  const int t = threadIdx.x;
  const int lane = t & 63;
  const int wid = t >> 6;                   // 0..3
  const int blk = blockIdx.x;
  const int b = blk & 7;
  const int ks = blk >> 3;                  // 0..63 (32-k slice)
  const int j0 = ks * 32;

  const float4 wv4 = reinterpret_cast<const float4*>(w)[lane];

#pragma unroll
  for (int r8 = 0; r8 < 8; ++r8) {
    const int r = wid * 8 + r8;
    const size_t row = (size_t)b * LK + j0 + r;
    const float4 kv = reinterpret_cast<const float4*>(key + row * DD)[lane];
    float s = kv.x * wv4.x + kv.y * wv4.y + kv.z * wv4.z + kv.w * wv4.w;
#pragma unroll
    for (int off = 32; off; off >>= 1) s += __shfl_xor(s, off);
    const float e = __expf(s);              // |K·w| small: no max-shift needed
    if (lane == 0) { e_s[r] = e; eb[row] = f2bf(e); }
  }
  __syncthreads();

#pragma unroll
  for (int g = 0; g < 8; ++g) {
    const int jr = g * 4 + wid;
    const size_t row = (size_t)b * LK + j0 + jr;
    const float4 vv = reinterpret_cast<const float4*>(value + row * DD)[lane];
    const float e = e_s[jr];
    ushort4 u;
    u.x = f2bf(e * vv.x);
    u.y = f2bf(e * vv.y);
    u.z = f2bf(e * vv.z);
    u.w = f2bf(e * vv.w);
    *reinterpret_cast<ushort4*>(&t_s[jr][lane * 4]) = u;
  }
  __syncthreads();

  // frag gather: lane holds B[k=8*(lane>>4)+i][d=n*16+(lane&15)]
  const int lr = lane & 15;
  const int lj = lane >> 4;
#pragma unroll
  for (int n4 = 0; n4 < 4; ++n4) {
    const int n = wid * 4 + n4;
    ushort8v va;
#pragma unroll
    for (int i = 0; i < 8; ++i) va[i] = t_s[lj * 8 + i][n * 16 + lr];
    *reinterpret_cast<ushort8v*>(
        evB + ((size_t)((b * 64 + ks) * 16 + n) * 64 + lane) * 8) = va;
  }
}

// ---------------- Kernel 2: mask-streaming masked GEMM ------------------------
// grid 256: blk = b + 8*(itile + 16*dh); 1 block/CU. 512 thr = 8 waves (2m x 4n).
__global__ __launch_bounds__(512, 1) void bah_gemm(
    const int* __restrict__ mask, const unsigned short* __restrict__ evB,
    const unsigned short* __restrict__ eb, float* __restrict__ out)
{
  __shared__ unsigned short A_s[3][128 * 64];  // 3-deep ring, 48 KB, rot-swizzled
  __shared__ float denom_s[128];

  const int t = threadIdx.x;
  const int lane = t & 63;
  const int wid = t >> 6;                   // 0..7
  const int wm = wid >> 2;                  // 0..1: 64-row half
  const int wn = wid & 3;                   // 0..3: 32-d quarter
  const int lr = lane & 15;
  const int lj = lane >> 4;

  const int blk = blockIdx.x;
  const int b = blk & 7;                    // batch -> XCD (evB L2-resident)
  const int rr = blk >> 3;
  const int i0 = (rr & 15) * 128;
  const int dh = rr >> 4;                   // 0..1: d half

  // ---- A staging: COALESCED. thread -> row sr (4 thr/row); lanes 0-3 read
  //      contiguous 64 B of one row; 4 loads j at +64 B stride cover 256 B. ----
  const int sr = t >> 2;                    // 0..127
  const int q = t & 3;
  const int* aptr = mask + ((size_t)b * LQ + i0 + sr) * LK + q * 4;
  // LDS write slots (ushort idx): k-ints kk = q*4 + j*16 -> 16B chunk c2 =
  // (q>>1)+2j, 8B half (q&1). Rotation swizzle: slot = (c2 + sr) & 7.
  int awr[4];
#pragma unroll
  for (int j = 0; j < 4; ++j)
    awr[j] = sr * 64 + ((((q >> 1) + 2 * j + sr) & 7) * 8) + (q & 1) * 4;

  // B frag pointers (pre-fragged evB): stride 8192 ushorts per 32-k slice
  const unsigned short* bB[2];
#pragma unroll
  for (int nn = 0; nn < 2; ++nn)
    bB[nn] = evB + ((size_t)(b * 64) * 16 + dh * 8 + wn * 2 + nn) * 512 + lane * 8;
  const unsigned short* ebb = eb + b * LK + lj * 8;

  // A frag read offsets: row = wm*64 + m*16 + lr; chunk (h*4+lj) rotated by row
  int afo[4][2];
#pragma unroll
  for (int m = 0; m < 4; ++m) {
    const int row = wm * 64 + m * 16 + lr;
#pragma unroll
    for (int h = 0; h < 2; ++h)
      afo[m][h] = row * 64 + (((h * 4 + lj + row) & 7) * 8);
  }

  f32x4 acc[4][2] = {};
  f32x4 accd[4] = {};
  const short8v z8 = {};

  short8v bfr[2][2][2];                     // [buf][h][nn] — 1 step ahead
  short8v efr[2][2] = {{z8, z8}, {z8, z8}};

  // ---- prologue: A(0)->ring0; A(1)->regs; B(0)/e(0)->reg buf0 ----
#pragma unroll
  for (int j = 0; j < 4; ++j) {
    const int4 p = *reinterpret_cast<const int4*>(aptr + j * 16);
    *reinterpret_cast<uint2*>(&A_s[0][awr[j]]) = pack_mask4(p);
  }
  int4 aC0 = *reinterpret_cast<const int4*>(aptr + 64 + 0);
  int4 aC1 = *reinterpret_cast<const int4*>(aptr + 64 + 16);
  int4 aC2 = *reinterpret_cast<const int4*>(aptr + 64 + 32);
  int4 aC3 = *reinterpret_cast<const int4*>(aptr + 64 + 48);
#pragma unroll
  for (int h = 0; h < 2; ++h) {
#pragma unroll
    for (int nn = 0; nn < 2; ++nn)
      bfr[0][h][nn] = *reinterpret_cast<const short8v*>(bB[nn] + (size_t)h * 8192);
    if (wn == 0 && lr == 0)
      efr[0][h] = *reinterpret_cast<const short8v*>(ebb + h * 32);
  }
  __syncthreads();

#pragma unroll 2
  for (int tt = 0; tt < 32; ++tt) {
    const int cur = tt & 1;
    const int nxt = cur ^ 1;
    const int bufC = tt % 3;
    const int bufW = (tt + 1) % 3;

    // ---- issue: A(t+2), B(t+1), e(t+1) (cross barrier via counted vmcnt) ----
    const int k2 = ((tt + 2) & 31) * 64;    // wrap: dead loads, harmless
    const int4 aN0 = *reinterpret_cast<const int4*>(aptr + k2 + 0);
    const int4 aN1 = *reinterpret_cast<const int4*>(aptr + k2 + 16);
    const int4 aN2 = *reinterpret_cast<const int4*>(aptr + k2 + 32);
    const int4 aN3 = *reinterpret_cast<const int4*>(aptr + k2 + 48);
    const int kn = ((tt + 1) & 31) * 2;
#pragma unroll
    for (int h = 0; h < 2; ++h) {
#pragma unroll
      for (int nn = 0; nn < 2; ++nn)
        bfr[nxt][h][nn] = *reinterpret_cast<const short8v*>(
            bB[nn] + (size_t)(kn + h) * 8192);
      short8v ev = z8;
      if (wn == 0 && lr == 0)
        ev = *reinterpret_cast<const short8v*>(ebb + (kn + h) * 32);
      efr[nxt][h] = ev;
    }
    __builtin_amdgcn_sched_barrier(0);

    // ---- write A(t+1) from regs; certify with lgkm + barrier only ----
    *reinterpret_cast<uint2*>(&A_s[bufW][awr[0]]) = pack_mask4(aC0);
    *reinterpret_cast<uint2*>(&A_s[bufW][awr[1]]) = pack_mask4(aC1);
    *reinterpret_cast<uint2*>(&A_s[bufW][awr[2]]) = pack_mask4(aC2);
    *reinterpret_cast<uint2*>(&A_s[bufW][awr[3]]) = pack_mask4(aC3);
    asm volatile("s_waitcnt lgkmcnt(0)" ::: "memory");
    __builtin_amdgcn_sched_barrier(0);
    __builtin_amdgcn_s_barrier();
    __builtin_amdgcn_sched_barrier(0);

    // ---- compute tile t from LDS-A + reg-B ----
#pragma unroll
    for (int h = 0; h < 2; ++h) {
      short8v af[4];
#pragma unroll
      for (int m = 0; m < 4; ++m)
        af[m] = *reinterpret_cast<const short8v*>(&A_s[bufC][afo[m][h]]);
      __builtin_amdgcn_s_setprio(1);
      if (wn == 0) {
#pragma unroll
        for (int m = 0; m < 4; ++m)
          accd[m] = __builtin_amdgcn_mfma_f32_16x16x32_bf16(
              af[m], efr[cur][h], accd[m], 0, 0, 0);
      }
#pragma unroll
      for (int m = 0; m < 4; ++m)
#pragma unroll
        for (int nn = 0; nn < 2; ++nn)
          acc[m][nn] = __builtin_amdgcn_mfma_f32_16x16x32_bf16(
              af[m], bfr[cur][h][nn], acc[m][nn], 0, 0, 0);
      __builtin_amdgcn_s_setprio(0);
    }
    aC0 = aN0; aC1 = aN1; aC2 = aN2; aC3 = aN3;
  }

  // ---- denominator broadcast (C col 0 lives in lanes with lr==0) ----
  if (wn == 0 && lr == 0) {
#pragma unroll
    for (int m = 0; m < 4; ++m)
#pragma unroll
      for (int qq = 0; qq < 4; ++qq)
        denom_s[wm * 64 + m * 16 + lj * 4 + qq] = accd[m][qq];
  }
  __syncthreads();

  // ---- epilogue: divide and store (C layout: col=lane&15, row=lj*4+q) ----
#pragma unroll
  for (int m = 0; m < 4; ++m) {
    const int row0 = wm * 64 + m * 16 + lj * 4;
    float inv[4];
#pragma unroll
    for (int qq = 0; qq < 4; ++qq) {
      const float dn = denom_s[row0 + qq];
      inv[qq] = (dn != 0.f) ? 1.f / dn : 0.f;   // all-masked row: avoid NaN
    }
#pragma unroll
    for (int nn = 0; nn < 2; ++nn) {
      const int col = dh * 128 + wn * 32 + nn * 16 + lr;
#pragma unroll
      for (int qq = 0; qq < 4; ++qq)
        out[((size_t)b * LQ + (i0 + row0 + qq)) * DD + col] = acc[m][nn][qq] * inv[qq];
    }
  }
}

extern "C" void kernel_launch(void* const* d_in, const int* in_sizes, int n_in,
                              void* d_out, int out_size, void* d_ws, size_t ws_size,
                              hipStream_t stream) {
  // inputs: 0=query (unused: softmax shift-invariance), 1=key, 2=value, 3=mask, 4=w_align
  const float* key   = (const float*)d_in[1];
  const float* value = (const float*)d_in[2];
  const int*   mask  = (const int*)d_in[3];
  const float* w     = (const float*)d_in[4];
  float* out = (float*)d_out;

  unsigned short* evB = (unsigned short*)d_ws;                              // 8 MB
  unsigned short* eb  = (unsigned short*)((char*)d_ws + (size_t)NB * DD * LK * 2);

  bah_precompute<<<NB * (LK / 32), 256, 0, stream>>>(key, value, w, evB, eb);
  bah_gemm<<<256, 512, 0, stream>>>(mask, evB, eb, out);
}